// Round 5
// baseline (535.593 us; speedup 1.0000x reference)
//
#include <hip/hip_runtime.h>

#define N_NODES 100000
#define D_FEAT  128
#define N_EDGES 1600000
#define EPSBN   1e-5f
#define SLOPE   0.01f

typedef __attribute__((ext_vector_type(8))) short bf16x8;
typedef __attribute__((ext_vector_type(4))) float f32x4;
typedef unsigned short u16;
typedef unsigned int   u32;

__device__ __forceinline__ u16 f2bf(float f) {
    u32 x = __float_as_uint(f);
    u32 r = (x + 0x7fffu + ((x >> 16) & 1u)) >> 16;
    return (u16)r;
}
__device__ __forceinline__ float bf_lo(u32 w) { return __uint_as_float(w << 16); }
__device__ __forceinline__ float bf_hi(u32 w) { return __uint_as_float(w & 0xffff0000u); }

// ---------------- setup kernels ----------------

__global__ void k_init(int* deg_cnt, float* stats) {
    int i = blockIdx.x * 256 + threadIdx.x;
    if (i < N_NODES) deg_cnt[i] = 0;
    if (i < 1024) stats[i] = 0.f;
}

__global__ void k_deg(const int* __restrict__ dst, int* __restrict__ deg_cnt) {
    int e = blockIdx.x * 256 + threadIdx.x;
    if (e < N_EDGES) atomicAdd(&deg_cnt[dst[e]], 1);
}

__global__ void k_scanA(const int* __restrict__ cnt, int* __restrict__ bsums) {
    __shared__ int red[256];
    int i = blockIdx.x * 256 + threadIdx.x;
    red[threadIdx.x] = (i < N_NODES) ? cnt[i] : 0;
    __syncthreads();
    for (int s = 128; s > 0; s >>= 1) {
        if (threadIdx.x < s) red[threadIdx.x] += red[threadIdx.x + s];
        __syncthreads();
    }
    if (threadIdx.x == 0) bsums[blockIdx.x] = red[0];
}

__global__ void k_scanB(int* bsums, int nb) {  // exclusive scan in place
    __shared__ int sc[512];
    int t = threadIdx.x;
    sc[t] = (t < nb) ? bsums[t] : 0;
    __syncthreads();
    for (int off = 1; off < 512; off <<= 1) {
        int add = (t >= off) ? sc[t - off] : 0;
        __syncthreads();
        sc[t] += add;
        __syncthreads();
    }
    if (t < nb) bsums[t] = (t == 0) ? 0 : sc[t - 1];
}

__global__ void k_scanC(const int* __restrict__ cnt, const int* __restrict__ bsums_ex,
                        int* __restrict__ row_start, int* __restrict__ cursor,
                        float* __restrict__ dinv) {
    __shared__ int sc[256];
    int t = threadIdx.x;
    int i = blockIdx.x * 256 + t;
    int c = (i < N_NODES) ? cnt[i] : 0;
    sc[t] = c;
    __syncthreads();
    for (int off = 1; off < 256; off <<= 1) {
        int add = (t >= off) ? sc[t - off] : 0;
        __syncthreads();
        sc[t] += add;
        __syncthreads();
    }
    if (i < N_NODES) {
        int excl = sc[t] - c + bsums_ex[blockIdx.x];
        row_start[i] = excl;
        cursor[i]    = excl;
        dinv[i]      = rsqrtf((float)(c + 1));
    }
}

__global__ void k_csrfill(const int* __restrict__ src, const int* __restrict__ dst,
                          int* __restrict__ cursor, int* __restrict__ csr_src) {
    int e = blockIdx.x * 256 + threadIdx.x;
    if (e >= N_EDGES) return;
    int s = src[e], d = dst[e];
    int slot = atomicAdd(&cursor[d], 1);
    csr_src[slot] = s;
}

// Pre-swizzle W (128x128 f32, row-major W[k][n]) into MFMA B-fragment order (bf16):
// frag t = (kc*8+nt)*64+lane holds 8 bf16: W[kc*32+(lane>>4)*8+j][nt*16+(lane&15)]
__global__ void k_swz(const float* __restrict__ W, u16* __restrict__ Wz) {
    int t = blockIdx.x * 256 + threadIdx.x;  // 0..2047
    int lane = t & 63, frag = t >> 6;
    int nt = frag & 7, kc = frag >> 3;
    int n  = nt * 16 + (lane & 15);
    int kb = kc * 32 + (lane >> 4) * 8;
    u16 tmp[8];
#pragma unroll
    for (int j = 0; j < 8; ++j) tmp[j] = f2bf(W[(kb + j) * 128 + n]);
#pragma unroll
    for (int j = 0; j < 8; ++j) Wz[t * 8 + j] = tmp[j];
}

// ---- GEMM: Hb[M x 128](bf16) = (act(A) @ W) * dinv[row] ; FUSE: act = leaky(A*scale+shift)
// dinv-row-fold: downstream agg needs h' = h * dinv[row]; do it in the epilogue for free.

template <bool FUSE>
__global__ __launch_bounds__(256) void k_gemm(const float* __restrict__ A,
                                              const u16* __restrict__ Wz,
                                              const float* __restrict__ scale,
                                              const float* __restrict__ shift,
                                              const float* __restrict__ dinv,
                                              u16* __restrict__ Hb, int M) {
    __shared__ u16 wl[16384];  // 32 KB
    __shared__ float sLds[128], hLds[128];
    int tid = threadIdx.x;
    {
        const uint4* s4 = (const uint4*)Wz;
        uint4* d4 = (uint4*)wl;
        for (int i = tid; i < 2048; i += 256) d4[i] = s4[i];
    }
    if (FUSE && tid < 128) { sLds[tid] = scale[tid]; hLds[tid] = shift[tid]; }
    __syncthreads();
    int wave = tid >> 6, lane = tid & 63;
    long m0 = ((long)blockIdx.x * 4 + wave) * 16;
    if (m0 >= M) return;
    int mr = lane & 15, quad = lane >> 4;
    const float* arow = A + (size_t)(m0 + mr) * 128 + quad * 8;
    f32x4 acc[8] = {};
#pragma unroll
    for (int kc = 0; kc < 4; ++kc) {
        float4 a0 = *(const float4*)(arow + kc * 32);
        float4 a1 = *(const float4*)(arow + kc * 32 + 4);
        float av[8] = {a0.x, a0.y, a0.z, a0.w, a1.x, a1.y, a1.z, a1.w};
        if (FUSE) {
            int c = kc * 32 + quad * 8;
#pragma unroll
            for (int j = 0; j < 8; ++j) {
                float v = fmaf(av[j], sLds[c + j], hLds[c + j]);
                av[j] = v > 0.f ? v : v * SLOPE;
            }
        }
        bf16x8 af;
#pragma unroll
        for (int j = 0; j < 8; ++j) af[j] = (short)f2bf(av[j]);
        const u16* wb = wl + (kc * 4096 + lane * 8);  // fragment (kc,nt) at (kc*8+nt)*512
#pragma unroll
        for (int nt = 0; nt < 8; ++nt) {
            bf16x8 bf = *(const bf16x8*)(wb + nt * 512);
            acc[nt] = __builtin_amdgcn_mfma_f32_16x16x32_bf16(af, bf, acc[nt], 0, 0, 0);
        }
    }
    // C/D layout: col = lane&15, row = quad*4 + r ; scale row by dinv, store bf16
    float dr[4];
#pragma unroll
    for (int r = 0; r < 4; ++r) dr[r] = dinv[m0 + quad * 4 + r];
    u16* hb = Hb + (size_t)m0 * 128 + (lane & 15);
#pragma unroll
    for (int nt = 0; nt < 8; ++nt)
#pragma unroll
        for (int r = 0; r < 4; ++r)
            hb[(size_t)(quad * 4 + r) * 128 + nt * 16] = f2bf(acc[nt][r] * dr[r]);
}

// ---------------- aggregation ----------------
// One wave per node. Row = 256B bf16 = 16 uint4; 16 lanes per row, 4 row-groups
// per wave -> each load instruction gathers 4 rows, 4 loads in flight per iter.
// AGG[d] = dinv[d] * (sum_{s in N(d)} h'[s] + h'[d])   (norm folded into h')

__device__ __forceinline__ void accum8(float* acc, uint4 w, float wt) {
    acc[0] = fmaf(bf_lo(w.x), wt, acc[0]);
    acc[1] = fmaf(bf_hi(w.x), wt, acc[1]);
    acc[2] = fmaf(bf_lo(w.y), wt, acc[2]);
    acc[3] = fmaf(bf_hi(w.y), wt, acc[3]);
    acc[4] = fmaf(bf_lo(w.z), wt, acc[4]);
    acc[5] = fmaf(bf_hi(w.z), wt, acc[5]);
    acc[6] = fmaf(bf_lo(w.w), wt, acc[6]);
    acc[7] = fmaf(bf_hi(w.w), wt, acc[7]);
}

__global__ __launch_bounds__(256) void k_agg(const uint4* __restrict__ Hb4,  // row s at [s*16]
                                             const int* __restrict__ row_start,
                                             const int* __restrict__ cnt,
                                             const float* __restrict__ dinv,
                                             const int* __restrict__ csr_src,
                                             float* __restrict__ AGG) {
    int wave = threadIdx.x >> 6, lane = threadIdx.x & 63;
    int node = blockIdx.x * 4 + wave;  // 25000*4 = 100000 exact
    int g = lane >> 4, f = lane & 15;
    int start = row_start[node];
    int num   = cnt[node];
    float di  = dinv[node];
    uint4 selfw = Hb4[(size_t)node * 16 + f];
    float acc[8] = {0.f, 0.f, 0.f, 0.f, 0.f, 0.f, 0.f, 0.f};
    for (int base = 0; base < num; base += 64) {
        int nb = num - base; if (nb > 64) nb = 64;
        int pk = (lane < nb) ? csr_src[start + base + lane] : 0;
        for (int j = 0; j < nb; j += 16) {
            int j0 = j + g, j1 = j + 4 + g, j2 = j + 8 + g, j3 = j + 12 + g;
            int s0 = __shfl(pk, j0), s1 = __shfl(pk, j1);
            int s2 = __shfl(pk, j2), s3 = __shfl(pk, j3);
            float w0 = j0 < nb ? 1.f : 0.f, w1 = j1 < nb ? 1.f : 0.f;
            float w2 = j2 < nb ? 1.f : 0.f, w3 = j3 < nb ? 1.f : 0.f;
            uint4 a0 = Hb4[(size_t)s0 * 16 + f];
            uint4 a1 = Hb4[(size_t)s1 * 16 + f];
            uint4 a2 = Hb4[(size_t)s2 * 16 + f];
            uint4 a3 = Hb4[(size_t)s3 * 16 + f];
            accum8(acc, a0, w0);
            accum8(acc, a1, w1);
            accum8(acc, a2, w2);
            accum8(acc, a3, w3);
        }
    }
    // reduce across the 4 row-groups (lanes f, f+16, f+32, f+48)
#pragma unroll
    for (int i = 0; i < 8; ++i) {
        acc[i] += __shfl_xor(acc[i], 16);
        acc[i] += __shfl_xor(acc[i], 32);
    }
    accum8(acc, selfw, 1.f);          // + h'[d]
#pragma unroll
    for (int i = 0; i < 8; ++i) acc[i] *= di;
    float* outp = AGG + (size_t)node * 128 + f * 8;
    if (g == 0) {
        float4 lo; lo.x = acc[0]; lo.y = acc[1]; lo.z = acc[2]; lo.w = acc[3];
        *(float4*)outp = lo;
    } else if (g == 1) {
        float4 hi; hi.x = acc[4]; hi.y = acc[5]; hi.z = acc[6]; hi.w = acc[7];
        *(float4*)(outp + 4) = hi;
    }
}

// ---------------- batch norm ----------------

__global__ void k_bnstats(const float* __restrict__ AGG, float* __restrict__ sums,
                          float* __restrict__ sumsq) {
    __shared__ float red[256];
    int col  = threadIdx.x & 127;
    int half = threadIdx.x >> 7;
    long r0 = (long)blockIdx.x * 400 + half;  // 250 blocks * 400 rows = 100000
    float s = 0.f, s2 = 0.f;
    for (int k = 0; k < 400; k += 2) {
        float v = AGG[(r0 + k) * 128 + col];
        s += v;
        s2 = fmaf(v, v, s2);
    }
    red[threadIdx.x] = s; __syncthreads();
    if (threadIdx.x < 128) atomicAdd(&sums[col], red[threadIdx.x] + red[threadIdx.x + 128]);
    __syncthreads();
    red[threadIdx.x] = s2; __syncthreads();
    if (threadIdx.x < 128) atomicAdd(&sumsq[col], red[threadIdx.x] + red[threadIdx.x + 128]);
}

__global__ void k_bnfin(const float* __restrict__ sums, const float* __restrict__ sumsq,
                        const float* __restrict__ g, const float* __restrict__ be,
                        float* __restrict__ scale, float* __restrict__ shift) {
    int c = threadIdx.x;  // 128 threads
    float mean = sums[c] * (1.f / N_NODES);
    float var  = sumsq[c] * (1.f / N_NODES) - mean * mean;
    float rstd = rsqrtf(var + EPSBN);
    float gg = g[c] * rstd;
    scale[c] = gg;
    shift[c] = be[c] - mean * gg;
}

// out = leaky(agg*scale + shift + x), f32 out
__global__ void k_ew2(const float* __restrict__ AGG, const float* __restrict__ scale,
                      const float* __restrict__ shift, const float* __restrict__ x,
                      float* __restrict__ out) {
    long i = (long)blockIdx.x * 256 + threadIdx.x;
    int c2 = (int)(i & 63);
    float2 v  = ((const float2*)AGG)[i];
    float2 sc = ((const float2*)scale)[c2];
    float2 sh = ((const float2*)shift)[c2];
    float2 xv = ((const float2*)x)[i];
    float2 o;
    o.x = fmaf(v.x, sc.x, sh.x) + xv.x; o.x = o.x > 0.f ? o.x : o.x * SLOPE;
    o.y = fmaf(v.y, sc.y, sh.y) + xv.y; o.y = o.y > 0.f ? o.y : o.y * SLOPE;
    ((float2*)out)[i] = o;
}

// ---------------- launch ----------------

extern "C" void kernel_launch(void* const* d_in, const int* in_sizes, int n_in,
                              void* d_out, int out_size, void* d_ws, size_t ws_size,
                              hipStream_t stream) {
    const float* x   = (const float*)d_in[0];
    const int*   ei  = (const int*)d_in[1];
    const float* W1  = (const float*)d_in[2];
    const float* g1  = (const float*)d_in[4];
    const float* be1 = (const float*)d_in[5];
    const float* W2  = (const float*)d_in[6];
    const float* g2  = (const float*)d_in[8];
    const float* be2 = (const float*)d_in[9];
    const int* src = ei;
    const int* dst = ei + N_EDGES;

    float* out = (float*)d_out;
    u16*   Hb  = (u16*)d_out;  // 25.6 MB bf16 H lives in d_out until ew2 overwrites it

    char* p = (char*)d_ws;
    float* bufA    = (float*)p; p += (size_t)N_NODES * 128 * 4;  // 51.2 MB (AGG1 then AGG2)
    int*   csr_src = (int*)p;   p += (size_t)N_EDGES * 4;        // 6.4 MB
    int*   deg_cnt = (int*)p;   p += (size_t)N_NODES * 4;
    int*   row_st  = (int*)p;   p += (size_t)N_NODES * 4;
    int*   cursor  = (int*)p;   p += (size_t)N_NODES * 4;
    float* dinv    = (float*)p; p += (size_t)N_NODES * 4;
    int*   bsums   = (int*)p;   p += 512 * 4;
    float* stats   = (float*)p; p += 1024 * 4;
    u16*   wz1     = (u16*)p;   p += 16384 * 2;
    u16*   wz2     = (u16*)p;   p += 16384 * 2;

    float* sums1 = stats,       *sq1 = stats + 128, *scale1 = stats + 256, *shift1 = stats + 384;
    float* sums2 = stats + 512, *sq2 = stats + 640, *scale2 = stats + 768, *shift2 = stats + 896;

    // graph setup (shared by both layers)
    k_init<<<391, 256, 0, stream>>>(deg_cnt, stats);
    k_deg<<<6250, 256, 0, stream>>>(dst, deg_cnt);
    k_scanA<<<391, 256, 0, stream>>>(deg_cnt, bsums);
    k_scanB<<<1, 512, 0, stream>>>(bsums, 391);
    k_scanC<<<391, 256, 0, stream>>>(deg_cnt, bsums, row_st, cursor, dinv);
    k_csrfill<<<6250, 256, 0, stream>>>(src, dst, cursor, csr_src);
    k_swz<<<8, 256, 0, stream>>>(W1, wz1);
    k_swz<<<8, 256, 0, stream>>>(W2, wz2);

    // layer 1:  Hb1 = (x@W1)*dinv -> d_out (bf16),  AGG1 -> bufA
    k_gemm<false><<<1563, 256, 0, stream>>>(x, wz1, nullptr, nullptr, dinv, Hb, N_NODES);
    k_agg<<<25000, 256, 0, stream>>>((const uint4*)Hb, row_st, deg_cnt, dinv, csr_src, bufA);
    k_bnstats<<<250, 256, 0, stream>>>(bufA, sums1, sq1);
    k_bnfin<<<1, 128, 0, stream>>>(sums1, sq1, g1, be1, scale1, shift1);

    // layer 2:  Hb2 = (leaky(BN1(AGG1))@W2)*dinv -> d_out;  AGG2 -> bufA
    k_gemm<true><<<1563, 256, 0, stream>>>(bufA, wz2, scale1, shift1, dinv, Hb, N_NODES);
    k_agg<<<25000, 256, 0, stream>>>((const uint4*)Hb, row_st, deg_cnt, dinv, csr_src, bufA);
    k_bnstats<<<250, 256, 0, stream>>>(bufA, sums2, sq2);
    k_bnfin<<<1, 128, 0, stream>>>(sums2, sq2, g2, be2, scale2, shift2);
    k_ew2<<<25000, 256, 0, stream>>>(bufA, scale2, shift2, x, out);
}

// Round 6
// 454.970 us; speedup vs baseline: 1.1772x; 1.1772x over previous
//
#include <hip/hip_runtime.h>

#define N_NODES 100000
#define D_FEAT  128
#define N_EDGES 1600000
#define EPSBN   1e-5f
#define SLOPE   0.01f

#define NBUCK   782          // ceil(100000 / 128) dst-buckets (128 nodes each)
#define PBLK    256          // partition blocks
#define CHUNK   6250         // edges per partition block (256*6250 = 1.6M exact)

typedef __attribute__((ext_vector_type(8))) short bf16x8;
typedef __attribute__((ext_vector_type(4))) float f32x4;
typedef unsigned short u16;
typedef unsigned int   u32;

__device__ __forceinline__ u16 f2bf(float f) {
    u32 x = __float_as_uint(f);
    u32 r = (x + 0x7fffu + ((x >> 16) & 1u)) >> 16;
    return (u16)r;
}
__device__ __forceinline__ float bf_lo(u32 w) { return __uint_as_float(w << 16); }
__device__ __forceinline__ float bf_hi(u32 w) { return __uint_as_float(w & 0xffff0000u); }

// ---------------- setup kernels ----------------

__global__ void k_init(int* deg_cnt, float* stats) {
    int i = blockIdx.x * 256 + threadIdx.x;
    if (i < N_NODES) deg_cnt[i] = 0;
    if (i < 1024) stats[i] = 0.f;
}

__global__ void k_deg(const int* __restrict__ dst, int* __restrict__ deg_cnt) {
    int e = blockIdx.x * 256 + threadIdx.x;
    if (e < N_EDGES) atomicAdd(&deg_cnt[dst[e]], 1);
}

__global__ void k_scanA(const int* __restrict__ cnt, int* __restrict__ bsums) {
    __shared__ int red[256];
    int i = blockIdx.x * 256 + threadIdx.x;
    red[threadIdx.x] = (i < N_NODES) ? cnt[i] : 0;
    __syncthreads();
    for (int s = 128; s > 0; s >>= 1) {
        if (threadIdx.x < s) red[threadIdx.x] += red[threadIdx.x + s];
        __syncthreads();
    }
    if (threadIdx.x == 0) bsums[blockIdx.x] = red[0];
}

__global__ void k_scanB(int* bsums, int nb) {  // exclusive scan in place
    __shared__ int sc[512];
    int t = threadIdx.x;
    sc[t] = (t < nb) ? bsums[t] : 0;
    __syncthreads();
    for (int off = 1; off < 512; off <<= 1) {
        int add = (t >= off) ? sc[t - off] : 0;
        __syncthreads();
        sc[t] += add;
        __syncthreads();
    }
    if (t < nb) bsums[t] = (t == 0) ? 0 : sc[t - 1];
}

__global__ void k_scanC(const int* __restrict__ cnt, const int* __restrict__ bsums_ex,
                        int* __restrict__ row_start, float* __restrict__ dinv) {
    __shared__ int sc[256];
    int t = threadIdx.x;
    int i = blockIdx.x * 256 + t;
    int c = (i < N_NODES) ? cnt[i] : 0;
    sc[t] = c;
    __syncthreads();
    for (int off = 1; off < 256; off <<= 1) {
        int add = (t >= off) ? sc[t - off] : 0;
        __syncthreads();
        sc[t] += add;
        __syncthreads();
    }
    if (i < N_NODES) {
        row_start[i] = sc[t] - c + bsums_ex[blockIdx.x];
        dinv[i]      = rsqrtf((float)(c + 1));
    }
}

// ---- CSR build, radix-partition style (kills the 100MB random-scatter writeback) ----

// P1: per-(chunk-block, bucket) histogram. hist[blk*NBUCK + b].
__global__ __launch_bounds__(256) void k_hist(const int* __restrict__ dst,
                                              int* __restrict__ hist) {
    __shared__ int h[NBUCK];
    int tid = threadIdx.x, blk = blockIdx.x;
    for (int i = tid; i < NBUCK; i += 256) h[i] = 0;
    __syncthreads();
    int e0 = blk * CHUNK;
    for (int e = e0 + tid; e < e0 + CHUNK; e += 256)
        atomicAdd(&h[dst[e] >> 7], 1);
    __syncthreads();
    for (int i = tid; i < NBUCK; i += 256) hist[blk * NBUCK + i] = h[i];
}

// P2: per-bucket exclusive scan over the 256 chunk-blocks; base = row_start[b*128].
// Overwrites hist in place with each block's write offset for this bucket.
__global__ __launch_bounds__(256) void k_boff(int* __restrict__ hist,
                                              const int* __restrict__ row_start) {
    __shared__ int sc[256];
    int t = threadIdx.x, b = blockIdx.x;   // b in [0, NBUCK)
    int c = hist[t * NBUCK + b];
    sc[t] = c;
    __syncthreads();
    for (int off = 1; off < 256; off <<= 1) {
        int add = (t >= off) ? sc[t - off] : 0;
        __syncthreads();
        sc[t] += add;
        __syncthreads();
    }
    hist[t * NBUCK + b] = row_start[b << 7] + sc[t] - c;
}

// P3: partition (src,dst) pairs into bucket-contiguous regions of tmp.
// Per-(block,bucket) writes are sequential slots; block's ~50KB of lines stay L2-hot.
__global__ __launch_bounds__(256) void k_part(const int* __restrict__ src,
                                              const int* __restrict__ dst,
                                              const int* __restrict__ hist,
                                              int2* __restrict__ tmp) {
    __shared__ int cur[NBUCK];
    int tid = threadIdx.x, blk = blockIdx.x;
    for (int i = tid; i < NBUCK; i += 256) cur[i] = hist[blk * NBUCK + i];
    __syncthreads();
    int e0 = blk * CHUNK;
    for (int e = e0 + tid; e < e0 + CHUNK; e += 256) {
        int s = src[e], d = dst[e];
        int slot = atomicAdd(&cur[d >> 7], 1);
        int2 pk; pk.x = s; pk.y = d;
        tmp[slot] = pk;
    }
}

// P4: exact within-bucket placement. One block per bucket; LDS cursors for the
// bucket's 128 nodes; scatter window = this bucket's ~8KB CSR region (L2-hot).
__global__ __launch_bounds__(256) void k_place(const int2* __restrict__ tmp,
                                               const int* __restrict__ row_start,
                                               int* __restrict__ csr_src) {
    __shared__ int lcur[128];
    int tid = threadIdx.x, b = blockIdx.x;
    if (tid < 128) {
        int node = (b << 7) + tid;
        lcur[tid] = (node < N_NODES) ? row_start[node] : 0;
    }
    __syncthreads();
    int lo = row_start[b << 7];
    int hi = (b == NBUCK - 1) ? N_EDGES : row_start[(b + 1) << 7];
    for (int e = lo + tid; e < hi; e += 256) {
        int2 pk = tmp[e];
        int slot = atomicAdd(&lcur[pk.y - (b << 7)], 1);
        csr_src[slot] = pk.x;
    }
}

// Pre-swizzle W (128x128 f32, row-major W[k][n]) into MFMA B-fragment order (bf16):
// frag t = (kc*8+nt)*64+lane holds 8 bf16: W[kc*32+(lane>>4)*8+j][nt*16+(lane&15)]
__global__ void k_swz(const float* __restrict__ W, u16* __restrict__ Wz) {
    int t = blockIdx.x * 256 + threadIdx.x;  // 0..2047
    int lane = t & 63, frag = t >> 6;
    int nt = frag & 7, kc = frag >> 3;
    int n  = nt * 16 + (lane & 15);
    int kb = kc * 32 + (lane >> 4) * 8;
    u16 tmp[8];
#pragma unroll
    for (int j = 0; j < 8; ++j) tmp[j] = f2bf(W[(kb + j) * 128 + n]);
#pragma unroll
    for (int j = 0; j < 8; ++j) Wz[t * 8 + j] = tmp[j];
}

// ---- GEMM: Hb[M x 128](bf16) = (act(A) @ W) * dinv[row] ; FUSE: act = leaky(A*scale+shift)

template <bool FUSE>
__global__ __launch_bounds__(256) void k_gemm(const float* __restrict__ A,
                                              const u16* __restrict__ Wz,
                                              const float* __restrict__ scale,
                                              const float* __restrict__ shift,
                                              const float* __restrict__ dinv,
                                              u16* __restrict__ Hb, int M) {
    __shared__ u16 wl[16384];  // 32 KB
    __shared__ float sLds[128], hLds[128];
    int tid = threadIdx.x;
    {
        const uint4* s4 = (const uint4*)Wz;
        uint4* d4 = (uint4*)wl;
        for (int i = tid; i < 2048; i += 256) d4[i] = s4[i];
    }
    if (FUSE && tid < 128) { sLds[tid] = scale[tid]; hLds[tid] = shift[tid]; }
    __syncthreads();
    int wave = tid >> 6, lane = tid & 63;
    long m0 = ((long)blockIdx.x * 4 + wave) * 16;
    if (m0 >= M) return;
    int mr = lane & 15, quad = lane >> 4;
    const float* arow = A + (size_t)(m0 + mr) * 128 + quad * 8;
    f32x4 acc[8] = {};
#pragma unroll
    for (int kc = 0; kc < 4; ++kc) {
        float4 a0 = *(const float4*)(arow + kc * 32);
        float4 a1 = *(const float4*)(arow + kc * 32 + 4);
        float av[8] = {a0.x, a0.y, a0.z, a0.w, a1.x, a1.y, a1.z, a1.w};
        if (FUSE) {
            int c = kc * 32 + quad * 8;
#pragma unroll
            for (int j = 0; j < 8; ++j) {
                float v = fmaf(av[j], sLds[c + j], hLds[c + j]);
                av[j] = v > 0.f ? v : v * SLOPE;
            }
        }
        bf16x8 af;
#pragma unroll
        for (int j = 0; j < 8; ++j) af[j] = (short)f2bf(av[j]);
        const u16* wb = wl + (kc * 4096 + lane * 8);  // fragment (kc,nt) at (kc*8+nt)*512
#pragma unroll
        for (int nt = 0; nt < 8; ++nt) {
            bf16x8 bf = *(const bf16x8*)(wb + nt * 512);
            acc[nt] = __builtin_amdgcn_mfma_f32_16x16x32_bf16(af, bf, acc[nt], 0, 0, 0);
        }
    }
    // C/D layout: col = lane&15, row = quad*4 + r ; scale row by dinv, store bf16
    float dr[4];
#pragma unroll
    for (int r = 0; r < 4; ++r) dr[r] = dinv[m0 + quad * 4 + r];
    u16* hb = Hb + (size_t)m0 * 128 + (lane & 15);
#pragma unroll
    for (int nt = 0; nt < 8; ++nt)
#pragma unroll
        for (int r = 0; r < 4; ++r)
            hb[(size_t)(quad * 4 + r) * 128 + nt * 16] = f2bf(acc[nt][r] * dr[r]);
}

// ---------------- aggregation ----------------
// One wave per node; row = 16 uint4; 4 row-groups per wave -> 4 gathers in flight.
// AGG[d] = dinv[d] * (sum_{s in N(d)} h'[s] + h'[d])   (norm folded into h')

__device__ __forceinline__ void accum8(float* acc, uint4 w, float wt) {
    acc[0] = fmaf(bf_lo(w.x), wt, acc[0]);
    acc[1] = fmaf(bf_hi(w.x), wt, acc[1]);
    acc[2] = fmaf(bf_lo(w.y), wt, acc[2]);
    acc[3] = fmaf(bf_hi(w.y), wt, acc[3]);
    acc[4] = fmaf(bf_lo(w.z), wt, acc[4]);
    acc[5] = fmaf(bf_hi(w.z), wt, acc[5]);
    acc[6] = fmaf(bf_lo(w.w), wt, acc[6]);
    acc[7] = fmaf(bf_hi(w.w), wt, acc[7]);
}

__global__ __launch_bounds__(256) void k_agg(const uint4* __restrict__ Hb4,
                                             const int* __restrict__ row_start,
                                             const int* __restrict__ cnt,
                                             const float* __restrict__ dinv,
                                             const int* __restrict__ csr_src,
                                             float* __restrict__ AGG) {
    int wave = threadIdx.x >> 6, lane = threadIdx.x & 63;
    int node = blockIdx.x * 4 + wave;  // 25000*4 = 100000 exact
    int g = lane >> 4, f = lane & 15;
    int start = row_start[node];
    int num   = cnt[node];
    float di  = dinv[node];
    uint4 selfw = Hb4[(size_t)node * 16 + f];
    float acc[8] = {0.f, 0.f, 0.f, 0.f, 0.f, 0.f, 0.f, 0.f};
    for (int base = 0; base < num; base += 64) {
        int nb = num - base; if (nb > 64) nb = 64;
        int pk = (lane < nb) ? csr_src[start + base + lane] : 0;
        for (int j = 0; j < nb; j += 16) {
            int j0 = j + g, j1 = j + 4 + g, j2 = j + 8 + g, j3 = j + 12 + g;
            int s0 = __shfl(pk, j0), s1 = __shfl(pk, j1);
            int s2 = __shfl(pk, j2), s3 = __shfl(pk, j3);
            float w0 = j0 < nb ? 1.f : 0.f, w1 = j1 < nb ? 1.f : 0.f;
            float w2 = j2 < nb ? 1.f : 0.f, w3 = j3 < nb ? 1.f : 0.f;
            uint4 a0 = Hb4[(size_t)s0 * 16 + f];
            uint4 a1 = Hb4[(size_t)s1 * 16 + f];
            uint4 a2 = Hb4[(size_t)s2 * 16 + f];
            uint4 a3 = Hb4[(size_t)s3 * 16 + f];
            accum8(acc, a0, w0);
            accum8(acc, a1, w1);
            accum8(acc, a2, w2);
            accum8(acc, a3, w3);
        }
    }
#pragma unroll
    for (int i = 0; i < 8; ++i) {
        acc[i] += __shfl_xor(acc[i], 16);
        acc[i] += __shfl_xor(acc[i], 32);
    }
    accum8(acc, selfw, 1.f);          // + h'[d]
#pragma unroll
    for (int i = 0; i < 8; ++i) acc[i] *= di;
    float* outp = AGG + (size_t)node * 128 + f * 8;
    if (g == 0) {
        float4 lo; lo.x = acc[0]; lo.y = acc[1]; lo.z = acc[2]; lo.w = acc[3];
        *(float4*)outp = lo;
    } else if (g == 1) {
        float4 hi; hi.x = acc[4]; hi.y = acc[5]; hi.z = acc[6]; hi.w = acc[7];
        *(float4*)(outp + 4) = hi;
    }
}

// ---------------- batch norm ----------------

__global__ void k_bnstats(const float* __restrict__ AGG, float* __restrict__ sums,
                          float* __restrict__ sumsq) {
    __shared__ float red[256];
    int col  = threadIdx.x & 127;
    int half = threadIdx.x >> 7;
    long r0 = (long)blockIdx.x * 400 + half;  // 250 blocks * 400 rows = 100000
    float s = 0.f, s2 = 0.f;
    for (int k = 0; k < 400; k += 2) {
        float v = AGG[(r0 + k) * 128 + col];
        s += v;
        s2 = fmaf(v, v, s2);
    }
    red[threadIdx.x] = s; __syncthreads();
    if (threadIdx.x < 128) atomicAdd(&sums[col], red[threadIdx.x] + red[threadIdx.x + 128]);
    __syncthreads();
    red[threadIdx.x] = s2; __syncthreads();
    if (threadIdx.x < 128) atomicAdd(&sumsq[col], red[threadIdx.x] + red[threadIdx.x + 128]);
}

__global__ void k_bnfin(const float* __restrict__ sums, const float* __restrict__ sumsq,
                        const float* __restrict__ g, const float* __restrict__ be,
                        float* __restrict__ scale, float* __restrict__ shift) {
    int c = threadIdx.x;  // 128 threads
    float mean = sums[c] * (1.f / N_NODES);
    float var  = sumsq[c] * (1.f / N_NODES) - mean * mean;
    float rstd = rsqrtf(var + EPSBN);
    float gg = g[c] * rstd;
    scale[c] = gg;
    shift[c] = be[c] - mean * gg;
}

// out = leaky(agg*scale + shift + x), f32 out
__global__ void k_ew2(const float* __restrict__ AGG, const float* __restrict__ scale,
                      const float* __restrict__ shift, const float* __restrict__ x,
                      float* __restrict__ out) {
    long i = (long)blockIdx.x * 256 + threadIdx.x;
    int c2 = (int)(i & 63);
    float2 v  = ((const float2*)AGG)[i];
    float2 sc = ((const float2*)scale)[c2];
    float2 sh = ((const float2*)shift)[c2];
    float2 xv = ((const float2*)x)[i];
    float2 o;
    o.x = fmaf(v.x, sc.x, sh.x) + xv.x; o.x = o.x > 0.f ? o.x : o.x * SLOPE;
    o.y = fmaf(v.y, sc.y, sh.y) + xv.y; o.y = o.y > 0.f ? o.y : o.y * SLOPE;
    ((float2*)out)[i] = o;
}

// ---------------- launch ----------------

extern "C" void kernel_launch(void* const* d_in, const int* in_sizes, int n_in,
                              void* d_out, int out_size, void* d_ws, size_t ws_size,
                              hipStream_t stream) {
    const float* x   = (const float*)d_in[0];
    const int*   ei  = (const int*)d_in[1];
    const float* W1  = (const float*)d_in[2];
    const float* g1  = (const float*)d_in[4];
    const float* be1 = (const float*)d_in[5];
    const float* W2  = (const float*)d_in[6];
    const float* g2  = (const float*)d_in[8];
    const float* be2 = (const float*)d_in[9];
    const int* src = ei;
    const int* dst = ei + N_EDGES;

    float* out = (float*)d_out;
    u16*   Hb  = (u16*)d_out;  // 25.6 MB bf16 H lives in d_out until ew2 overwrites it

    char* p = (char*)d_ws;
    float* bufA    = (float*)p; p += (size_t)N_NODES * 128 * 4;  // 51.2 MB (AGG1 then AGG2)
    int2*  tmp     = (int2*)p;  p += (size_t)N_EDGES * 8;        // 12.8 MB bucketed pairs
    int*   csr_src = (int*)p;   p += (size_t)N_EDGES * 4;        // 6.4 MB
    int*   hist    = (int*)p;   p += (size_t)PBLK * NBUCK * 4;   // 0.8 MB
    int*   deg_cnt = (int*)p;   p += (size_t)N_NODES * 4;
    int*   row_st  = (int*)p;   p += (size_t)N_NODES * 4;
    float* dinv    = (float*)p; p += (size_t)N_NODES * 4;
    int*   bsums   = (int*)p;   p += 512 * 4;
    float* stats   = (float*)p; p += 1024 * 4;
    u16*   wz1     = (u16*)p;   p += 16384 * 2;
    u16*   wz2     = (u16*)p;   p += 16384 * 2;

    float* sums1 = stats,       *sq1 = stats + 128, *scale1 = stats + 256, *shift1 = stats + 384;
    float* sums2 = stats + 512, *sq2 = stats + 640, *scale2 = stats + 768, *shift2 = stats + 896;

    // graph setup: deg -> row_start/dinv -> radix-partition CSR build
    k_init<<<391, 256, 0, stream>>>(deg_cnt, stats);
    k_deg<<<6250, 256, 0, stream>>>(dst, deg_cnt);
    k_scanA<<<391, 256, 0, stream>>>(deg_cnt, bsums);
    k_scanB<<<1, 512, 0, stream>>>(bsums, 391);
    k_scanC<<<391, 256, 0, stream>>>(deg_cnt, bsums, row_st, dinv);
    k_hist<<<PBLK, 256, 0, stream>>>(dst, hist);
    k_boff<<<NBUCK, 256, 0, stream>>>(hist, row_st);
    k_part<<<PBLK, 256, 0, stream>>>(src, dst, hist, tmp);
    k_place<<<NBUCK, 256, 0, stream>>>(tmp, row_st, csr_src);
    k_swz<<<8, 256, 0, stream>>>(W1, wz1);
    k_swz<<<8, 256, 0, stream>>>(W2, wz2);

    // layer 1:  Hb1 = (x@W1)*dinv -> d_out (bf16),  AGG1 -> bufA
    k_gemm<false><<<1563, 256, 0, stream>>>(x, wz1, nullptr, nullptr, dinv, Hb, N_NODES);
    k_agg<<<25000, 256, 0, stream>>>((const uint4*)Hb, row_st, deg_cnt, dinv, csr_src, bufA);
    k_bnstats<<<250, 256, 0, stream>>>(bufA, sums1, sq1);
    k_bnfin<<<1, 128, 0, stream>>>(sums1, sq1, g1, be1, scale1, shift1);

    // layer 2:  Hb2 = (leaky(BN1(AGG1))@W2)*dinv -> d_out;  AGG2 -> bufA
    k_gemm<true><<<1563, 256, 0, stream>>>(bufA, wz2, scale1, shift1, dinv, Hb, N_NODES);
    k_agg<<<25000, 256, 0, stream>>>((const uint4*)Hb, row_st, deg_cnt, dinv, csr_src, bufA);
    k_bnstats<<<250, 256, 0, stream>>>(bufA, sums2, sq2);
    k_bnfin<<<1, 128, 0, stream>>>(sums2, sq2, g2, be2, scale2, shift2);
    k_ew2<<<25000, 256, 0, stream>>>(bufA, scale2, shift2, x, out);
}

// Round 7
// 391.825 us; speedup vs baseline: 1.3669x; 1.1612x over previous
//
#include <hip/hip_runtime.h>

#define N_NODES 100000
#define D_FEAT  128
#define N_EDGES 1600000
#define EPSBN   1e-5f
#define SLOPE   0.01f

#define NBUCK   782          // ceil(100000 / 128) dst-buckets (128 nodes each)
#define PBLK    256          // partition blocks
#define CHUNK   6250         // edges per partition block (256*6250 = 1.6M exact)

typedef __attribute__((ext_vector_type(8))) short bf16x8;
typedef __attribute__((ext_vector_type(4))) float f32x4;
typedef unsigned short u16;
typedef unsigned int   u32;

__device__ __forceinline__ u16 f2bf(float f) {
    u32 x = __float_as_uint(f);
    u32 r = (x + 0x7fffu + ((x >> 16) & 1u)) >> 16;
    return (u16)r;
}
__device__ __forceinline__ float bf_lo(u32 w) { return __uint_as_float(w << 16); }
__device__ __forceinline__ float bf_hi(u32 w) { return __uint_as_float(w & 0xffff0000u); }

// ---------------- setup ----------------

__global__ void k_init(float* stats) {
    int i = blockIdx.x * 256 + threadIdx.x;
    if (i < 1024) stats[i] = 0.f;
}

// P1: per-(chunk-block, bucket) histogram in LDS. hist[blk*NBUCK + b].
__global__ __launch_bounds__(256) void k_hist(const int* __restrict__ dst,
                                              int* __restrict__ hist) {
    __shared__ int h[NBUCK];
    int tid = threadIdx.x, blk = blockIdx.x;
    for (int i = tid; i < NBUCK; i += 256) h[i] = 0;
    __syncthreads();
    int e0 = blk * CHUNK;
    for (int e = e0 + tid; e < e0 + CHUNK; e += 256)
        atomicAdd(&h[dst[e] >> 7], 1);
    __syncthreads();
    for (int i = tid; i < NBUCK; i += 256) hist[blk * NBUCK + i] = h[i];
}

// P2a: per-bucket exclusive scan over the 256 chunk-blocks (relative offsets);
// bucket total -> tot[b].
__global__ __launch_bounds__(256) void k_colscan(int* __restrict__ hist,
                                                 int* __restrict__ tot) {
    __shared__ int sc[256];
    int t = threadIdx.x, b = blockIdx.x;   // b in [0, NBUCK)
    int c = hist[t * NBUCK + b];
    sc[t] = c;
    __syncthreads();
    for (int off = 1; off < 256; off <<= 1) {
        int add = (t >= off) ? sc[t - off] : 0;
        __syncthreads();
        sc[t] += add;
        __syncthreads();
    }
    hist[t * NBUCK + b] = sc[t] - c;       // relative offset within bucket
    if (t == 255) tot[b] = sc[255];
}

// P2b: exclusive scan of the 782 bucket totals -> bucket_base[0..NBUCK].
__global__ __launch_bounds__(1024) void k_bscan(const int* __restrict__ tot,
                                                int* __restrict__ bucket_base) {
    __shared__ int sc[1024];
    int t = threadIdx.x;
    int v = (t < NBUCK) ? tot[t] : 0;
    sc[t] = v;
    __syncthreads();
    for (int off = 1; off < 1024; off <<= 1) {
        int add = (t >= off) ? sc[t - off] : 0;
        __syncthreads();
        sc[t] += add;
        __syncthreads();
    }
    if (t < NBUCK) bucket_base[t] = sc[t] - v;
    if (t == 0) bucket_base[NBUCK] = N_EDGES;
}

// P3: partition (src,dst) pairs into bucket-contiguous regions of tmp.
__global__ __launch_bounds__(256) void k_part(const int* __restrict__ src,
                                              const int* __restrict__ dst,
                                              const int* __restrict__ hist,
                                              const int* __restrict__ bucket_base,
                                              int2* __restrict__ tmp) {
    __shared__ int cur[NBUCK];
    int tid = threadIdx.x, blk = blockIdx.x;
    for (int i = tid; i < NBUCK; i += 256)
        cur[i] = bucket_base[i] + hist[blk * NBUCK + i];
    __syncthreads();
    int e0 = blk * CHUNK;
    for (int e = e0 + tid; e < e0 + CHUNK; e += 256) {
        int s = src[e], d = dst[e];
        int slot = atomicAdd(&cur[d >> 7], 1);
        int2 pk; pk.x = s; pk.y = d;
        tmp[slot] = pk;
    }
}

// P4: one block per bucket. Count 128 node degrees in LDS, LDS-scan ->
// deg/row_start/dinv (sequential writes), then place csr_src within the
// bucket's L2-hot ~16KB window. Replaces global-atomic k_deg + scans + k_place.
__global__ __launch_bounds__(256) void k_bucket(const int2* __restrict__ tmp,
                                                const int* __restrict__ bucket_base,
                                                int* __restrict__ deg_cnt,
                                                int* __restrict__ row_start,
                                                float* __restrict__ dinv,
                                                int* __restrict__ csr_src) {
    __shared__ int lcnt[128];
    __shared__ int sc[128];
    __shared__ int lcur[128];
    int tid = threadIdx.x, b = blockIdx.x;
    int lo = bucket_base[b], hi = bucket_base[b + 1];
    if (tid < 128) lcnt[tid] = 0;
    __syncthreads();
    for (int e = lo + tid; e < hi; e += 256)
        atomicAdd(&lcnt[tmp[e].y & 127], 1);
    __syncthreads();
    int c = (tid < 128) ? lcnt[tid] : 0;
    if (tid < 128) sc[tid] = c;
    __syncthreads();
    for (int off = 1; off < 128; off <<= 1) {
        int add = (tid < 128 && tid >= off) ? sc[tid - off] : 0;
        __syncthreads();
        if (tid < 128) sc[tid] += add;
        __syncthreads();
    }
    if (tid < 128) {
        int node = (b << 7) + tid;
        int excl = lo + sc[tid] - c;
        lcur[tid] = excl;
        if (node < N_NODES) {
            deg_cnt[node]   = c;
            row_start[node] = excl;
            dinv[node]      = rsqrtf((float)(c + 1));
        }
    }
    __syncthreads();
    for (int e = lo + tid; e < hi; e += 256) {
        int2 pk = tmp[e];
        int slot = atomicAdd(&lcur[pk.y & 127], 1);
        csr_src[slot] = pk.x;
    }
}

// Pre-swizzle W (128x128 f32, row-major W[k][n]) into MFMA B-fragment order (bf16):
// frag t = (kc*8+nt)*64+lane holds 8 bf16: W[kc*32+(lane>>4)*8+j][nt*16+(lane&15)]
__global__ void k_swz(const float* __restrict__ W, u16* __restrict__ Wz) {
    int t = blockIdx.x * 256 + threadIdx.x;  // 0..2047
    int lane = t & 63, frag = t >> 6;
    int nt = frag & 7, kc = frag >> 3;
    int n  = nt * 16 + (lane & 15);
    int kb = kc * 32 + (lane >> 4) * 8;
    u16 tmp[8];
#pragma unroll
    for (int j = 0; j < 8; ++j) tmp[j] = f2bf(W[(kb + j) * 128 + n]);
#pragma unroll
    for (int j = 0; j < 8; ++j) Wz[t * 8 + j] = tmp[j];
}

// ---- GEMM: Hb[M x 128](bf16) = (act(A) @ W) * dinv[row] ; FUSE: act = leaky(A*scale+shift)

template <bool FUSE>
__global__ __launch_bounds__(256) void k_gemm(const float* __restrict__ A,
                                              const u16* __restrict__ Wz,
                                              const float* __restrict__ scale,
                                              const float* __restrict__ shift,
                                              const float* __restrict__ dinv,
                                              u16* __restrict__ Hb, int M) {
    __shared__ u16 wl[16384];  // 32 KB
    __shared__ float sLds[128], hLds[128];
    int tid = threadIdx.x;
    {
        const uint4* s4 = (const uint4*)Wz;
        uint4* d4 = (uint4*)wl;
        for (int i = tid; i < 2048; i += 256) d4[i] = s4[i];
    }
    if (FUSE && tid < 128) { sLds[tid] = scale[tid]; hLds[tid] = shift[tid]; }
    __syncthreads();
    int wave = tid >> 6, lane = tid & 63;
    long m0 = ((long)blockIdx.x * 4 + wave) * 16;
    if (m0 >= M) return;
    int mr = lane & 15, quad = lane >> 4;
    const float* arow = A + (size_t)(m0 + mr) * 128 + quad * 8;
    f32x4 acc[8] = {};
#pragma unroll
    for (int kc = 0; kc < 4; ++kc) {
        float4 a0 = *(const float4*)(arow + kc * 32);
        float4 a1 = *(const float4*)(arow + kc * 32 + 4);
        float av[8] = {a0.x, a0.y, a0.z, a0.w, a1.x, a1.y, a1.z, a1.w};
        if (FUSE) {
            int c = kc * 32 + quad * 8;
#pragma unroll
            for (int j = 0; j < 8; ++j) {
                float v = fmaf(av[j], sLds[c + j], hLds[c + j]);
                av[j] = v > 0.f ? v : v * SLOPE;
            }
        }
        bf16x8 af;
#pragma unroll
        for (int j = 0; j < 8; ++j) af[j] = (short)f2bf(av[j]);
        const u16* wb = wl + (kc * 4096 + lane * 8);  // fragment (kc,nt) at (kc*8+nt)*512
#pragma unroll
        for (int nt = 0; nt < 8; ++nt) {
            bf16x8 bf = *(const bf16x8*)(wb + nt * 512);
            acc[nt] = __builtin_amdgcn_mfma_f32_16x16x32_bf16(af, bf, acc[nt], 0, 0, 0);
        }
    }
    // C/D layout: col = lane&15, row = quad*4 + r ; scale row by dinv, store bf16
    float dr[4];
#pragma unroll
    for (int r = 0; r < 4; ++r) dr[r] = dinv[m0 + quad * 4 + r];
    u16* hb = Hb + (size_t)m0 * 128 + (lane & 15);
#pragma unroll
    for (int nt = 0; nt < 8; ++nt)
#pragma unroll
        for (int r = 0; r < 4; ++r)
            hb[(size_t)(quad * 4 + r) * 128 + nt * 16] = f2bf(acc[nt][r] * dr[r]);
}

// ---------------- aggregation ----------------
// One wave per node; row = 16 uint4; 4 row-groups per wave -> 4 gathers in flight.
// AGG[d] = dinv[d] * (sum_{s in N(d)} h'[s] + h'[d])   (norm folded into h')

__device__ __forceinline__ void accum8(float* acc, uint4 w, float wt) {
    acc[0] = fmaf(bf_lo(w.x), wt, acc[0]);
    acc[1] = fmaf(bf_hi(w.x), wt, acc[1]);
    acc[2] = fmaf(bf_lo(w.y), wt, acc[2]);
    acc[3] = fmaf(bf_hi(w.y), wt, acc[3]);
    acc[4] = fmaf(bf_lo(w.z), wt, acc[4]);
    acc[5] = fmaf(bf_hi(w.z), wt, acc[5]);
    acc[6] = fmaf(bf_lo(w.w), wt, acc[6]);
    acc[7] = fmaf(bf_hi(w.w), wt, acc[7]);
}

__global__ __launch_bounds__(256) void k_agg(const uint4* __restrict__ Hb4,
                                             const int* __restrict__ row_start,
                                             const int* __restrict__ cnt,
                                             const float* __restrict__ dinv,
                                             const int* __restrict__ csr_src,
                                             float* __restrict__ AGG) {
    int wave = threadIdx.x >> 6, lane = threadIdx.x & 63;
    int node = blockIdx.x * 4 + wave;  // 25000*4 = 100000 exact
    int g = lane >> 4, f = lane & 15;
    int start = row_start[node];
    int num   = cnt[node];
    float di  = dinv[node];
    uint4 selfw = Hb4[(size_t)node * 16 + f];
    float acc[8] = {0.f, 0.f, 0.f, 0.f, 0.f, 0.f, 0.f, 0.f};
    for (int base = 0; base < num; base += 64) {
        int nb = num - base; if (nb > 64) nb = 64;
        int pk = (lane < nb) ? csr_src[start + base + lane] : 0;
        for (int j = 0; j < nb; j += 16) {
            int j0 = j + g, j1 = j + 4 + g, j2 = j + 8 + g, j3 = j + 12 + g;
            int s0 = __shfl(pk, j0), s1 = __shfl(pk, j1);
            int s2 = __shfl(pk, j2), s3 = __shfl(pk, j3);
            float w0 = j0 < nb ? 1.f : 0.f, w1 = j1 < nb ? 1.f : 0.f;
            float w2 = j2 < nb ? 1.f : 0.f, w3 = j3 < nb ? 1.f : 0.f;
            uint4 a0 = Hb4[(size_t)s0 * 16 + f];
            uint4 a1 = Hb4[(size_t)s1 * 16 + f];
            uint4 a2 = Hb4[(size_t)s2 * 16 + f];
            uint4 a3 = Hb4[(size_t)s3 * 16 + f];
            accum8(acc, a0, w0);
            accum8(acc, a1, w1);
            accum8(acc, a2, w2);
            accum8(acc, a3, w3);
        }
    }
#pragma unroll
    for (int i = 0; i < 8; ++i) {
        acc[i] += __shfl_xor(acc[i], 16);
        acc[i] += __shfl_xor(acc[i], 32);
    }
    accum8(acc, selfw, 1.f);          // + h'[d]
#pragma unroll
    for (int i = 0; i < 8; ++i) acc[i] *= di;
    float* outp = AGG + (size_t)node * 128 + f * 8;
    if (g == 0) {
        float4 lo; lo.x = acc[0]; lo.y = acc[1]; lo.z = acc[2]; lo.w = acc[3];
        *(float4*)outp = lo;
    } else if (g == 1) {
        float4 hi; hi.x = acc[4]; hi.y = acc[5]; hi.z = acc[6]; hi.w = acc[7];
        *(float4*)(outp + 4) = hi;
    }
}

// ---------------- batch norm ----------------

__global__ void k_bnstats(const float* __restrict__ AGG, float* __restrict__ sums,
                          float* __restrict__ sumsq) {
    __shared__ float red[256];
    int col  = threadIdx.x & 127;
    int half = threadIdx.x >> 7;
    long r0 = (long)blockIdx.x * 400 + half;  // 250 blocks * 400 rows = 100000
    float s = 0.f, s2 = 0.f;
    for (int k = 0; k < 400; k += 2) {
        float v = AGG[(r0 + k) * 128 + col];
        s += v;
        s2 = fmaf(v, v, s2);
    }
    red[threadIdx.x] = s; __syncthreads();
    if (threadIdx.x < 128) atomicAdd(&sums[col], red[threadIdx.x] + red[threadIdx.x + 128]);
    __syncthreads();
    red[threadIdx.x] = s2; __syncthreads();
    if (threadIdx.x < 128) atomicAdd(&sumsq[col], red[threadIdx.x] + red[threadIdx.x + 128]);
}

__global__ void k_bnfin(const float* __restrict__ sums, const float* __restrict__ sumsq,
                        const float* __restrict__ g, const float* __restrict__ be,
                        float* __restrict__ scale, float* __restrict__ shift) {
    int c = threadIdx.x;  // 128 threads
    float mean = sums[c] * (1.f / N_NODES);
    float var  = sumsq[c] * (1.f / N_NODES) - mean * mean;
    float rstd = rsqrtf(var + EPSBN);
    float gg = g[c] * rstd;
    scale[c] = gg;
    shift[c] = be[c] - mean * gg;
}

// out = leaky(agg*scale + shift + x), f32 out
__global__ void k_ew2(const float* __restrict__ AGG, const float* __restrict__ scale,
                      const float* __restrict__ shift, const float* __restrict__ x,
                      float* __restrict__ out) {
    long i = (long)blockIdx.x * 256 + threadIdx.x;
    int c2 = (int)(i & 63);
    float2 v  = ((const float2*)AGG)[i];
    float2 sc = ((const float2*)scale)[c2];
    float2 sh = ((const float2*)shift)[c2];
    float2 xv = ((const float2*)x)[i];
    float2 o;
    o.x = fmaf(v.x, sc.x, sh.x) + xv.x; o.x = o.x > 0.f ? o.x : o.x * SLOPE;
    o.y = fmaf(v.y, sc.y, sh.y) + xv.y; o.y = o.y > 0.f ? o.y : o.y * SLOPE;
    ((float2*)out)[i] = o;
}

// ---------------- launch ----------------

extern "C" void kernel_launch(void* const* d_in, const int* in_sizes, int n_in,
                              void* d_out, int out_size, void* d_ws, size_t ws_size,
                              hipStream_t stream) {
    const float* x   = (const float*)d_in[0];
    const int*   ei  = (const int*)d_in[1];
    const float* W1  = (const float*)d_in[2];
    const float* g1  = (const float*)d_in[4];
    const float* be1 = (const float*)d_in[5];
    const float* W2  = (const float*)d_in[6];
    const float* g2  = (const float*)d_in[8];
    const float* be2 = (const float*)d_in[9];
    const int* src = ei;
    const int* dst = ei + N_EDGES;

    float* out = (float*)d_out;
    u16*   Hb  = (u16*)d_out;  // 25.6 MB bf16 H lives in d_out until ew2 overwrites it

    char* p = (char*)d_ws;
    float* bufA    = (float*)p; p += (size_t)N_NODES * 128 * 4;  // 51.2 MB (AGG1 then AGG2)
    int2*  tmp     = (int2*)p;  p += (size_t)N_EDGES * 8;        // 12.8 MB bucketed pairs
    int*   csr_src = (int*)p;   p += (size_t)N_EDGES * 4;        // 6.4 MB
    int*   hist    = (int*)p;   p += (size_t)PBLK * NBUCK * 4;   // 0.8 MB
    int*   tot     = (int*)p;   p += 1024 * 4;
    int*   bbase   = (int*)p;   p += 1024 * 4;
    int*   deg_cnt = (int*)p;   p += (size_t)N_NODES * 4;
    int*   row_st  = (int*)p;   p += (size_t)N_NODES * 4;
    float* dinv    = (float*)p; p += (size_t)N_NODES * 4;
    float* stats   = (float*)p; p += 1024 * 4;
    u16*   wz1     = (u16*)p;   p += 16384 * 2;
    u16*   wz2     = (u16*)p;   p += 16384 * 2;

    float* sums1 = stats,       *sq1 = stats + 128, *scale1 = stats + 256, *shift1 = stats + 384;
    float* sums2 = stats + 512, *sq2 = stats + 640, *scale2 = stats + 768, *shift2 = stats + 896;

    // graph setup: histogram -> bucket bases -> partition -> per-bucket
    // degree-count/scan/place (all counting via LDS; no global atomics)
    k_init<<<4, 256, 0, stream>>>(stats);
    k_hist<<<PBLK, 256, 0, stream>>>(dst, hist);
    k_colscan<<<NBUCK, 256, 0, stream>>>(hist, tot);
    k_bscan<<<1, 1024, 0, stream>>>(tot, bbase);
    k_part<<<PBLK, 256, 0, stream>>>(src, dst, hist, bbase, tmp);
    k_bucket<<<NBUCK, 256, 0, stream>>>(tmp, bbase, deg_cnt, row_st, dinv, csr_src);
    k_swz<<<8, 256, 0, stream>>>(W1, wz1);
    k_swz<<<8, 256, 0, stream>>>(W2, wz2);

    // layer 1:  Hb1 = (x@W1)*dinv -> d_out (bf16),  AGG1 -> bufA
    k_gemm<false><<<1563, 256, 0, stream>>>(x, wz1, nullptr, nullptr, dinv, Hb, N_NODES);
    k_agg<<<25000, 256, 0, stream>>>((const uint4*)Hb, row_st, deg_cnt, dinv, csr_src, bufA);
    k_bnstats<<<250, 256, 0, stream>>>(bufA, sums1, sq1);
    k_bnfin<<<1, 128, 0, stream>>>(sums1, sq1, g1, be1, scale1, shift1);

    // layer 2:  Hb2 = (leaky(BN1(AGG1))@W2)*dinv -> d_out;  AGG2 -> bufA
    k_gemm<true><<<1563, 256, 0, stream>>>(bufA, wz2, scale1, shift1, dinv, Hb, N_NODES);
    k_agg<<<25000, 256, 0, stream>>>((const uint4*)Hb, row_st, deg_cnt, dinv, csr_src, bufA);
    k_bnstats<<<250, 256, 0, stream>>>(bufA, sums2, sq2);
    k_bnfin<<<1, 128, 0, stream>>>(sums2, sq2, g2, be2, scale2, shift2);
    k_ew2<<<25000, 256, 0, stream>>>(bufA, scale2, shift2, x, out);
}

// Round 8
// 362.504 us; speedup vs baseline: 1.4775x; 1.0809x over previous
//
#include <hip/hip_runtime.h>

#define N_NODES 100000
#define D_FEAT  128
#define N_EDGES 1600000
#define EPSBN   1e-5f
#define SLOPE   0.01f

#define NBUCK   782          // ceil(100000 / 128) dst-buckets (128 nodes each)
#define PBLK    256          // partition blocks
#define CHUNK   6250         // edges per partition block (256*6250 = 1.6M exact)

typedef __attribute__((ext_vector_type(8))) short bf16x8;
typedef __attribute__((ext_vector_type(4))) float f32x4;
typedef unsigned short u16;
typedef unsigned int   u32;

__device__ __forceinline__ u16 f2bf(float f) {
    u32 x = __float_as_uint(f);
    u32 r = (x + 0x7fffu + ((x >> 16) & 1u)) >> 16;
    return (u16)r;
}
__device__ __forceinline__ float bf_lo(u32 w) { return __uint_as_float(w << 16); }
__device__ __forceinline__ float bf_hi(u32 w) { return __uint_as_float(w & 0xffff0000u); }

// ---------------- setup ----------------

__global__ void k_init(float* stats) {
    int i = blockIdx.x * 256 + threadIdx.x;
    if (i < 1024) stats[i] = 0.f;
}

// P1: per-(chunk-block, bucket) histogram in LDS. hist[blk*NBUCK + b].
__global__ __launch_bounds__(256) void k_hist(const int* __restrict__ dst,
                                              int* __restrict__ hist) {
    __shared__ int h[NBUCK];
    int tid = threadIdx.x, blk = blockIdx.x;
    for (int i = tid; i < NBUCK; i += 256) h[i] = 0;
    __syncthreads();
    int e0 = blk * CHUNK;
    for (int e = e0 + tid; e < e0 + CHUNK; e += 256)
        atomicAdd(&h[dst[e] >> 7], 1);
    __syncthreads();
    for (int i = tid; i < NBUCK; i += 256) hist[blk * NBUCK + i] = h[i];
}

// P2a: per-bucket exclusive scan over the 256 chunk-blocks (relative offsets);
// bucket total -> tot[b].
__global__ __launch_bounds__(256) void k_colscan(int* __restrict__ hist,
                                                 int* __restrict__ tot) {
    __shared__ int sc[256];
    int t = threadIdx.x, b = blockIdx.x;   // b in [0, NBUCK)
    int c = hist[t * NBUCK + b];
    sc[t] = c;
    __syncthreads();
    for (int off = 1; off < 256; off <<= 1) {
        int add = (t >= off) ? sc[t - off] : 0;
        __syncthreads();
        sc[t] += add;
        __syncthreads();
    }
    hist[t * NBUCK + b] = sc[t] - c;       // relative offset within bucket
    if (t == 255) tot[b] = sc[255];
}

// P2b: exclusive scan of the 782 bucket totals -> bucket_base[0..NBUCK].
__global__ __launch_bounds__(1024) void k_bscan(const int* __restrict__ tot,
                                                int* __restrict__ bucket_base) {
    __shared__ int sc[1024];
    int t = threadIdx.x;
    int v = (t < NBUCK) ? tot[t] : 0;
    sc[t] = v;
    __syncthreads();
    for (int off = 1; off < 1024; off <<= 1) {
        int add = (t >= off) ? sc[t - off] : 0;
        __syncthreads();
        sc[t] += add;
        __syncthreads();
    }
    if (t < NBUCK) bucket_base[t] = sc[t] - v;
    if (t == 0) bucket_base[NBUCK] = N_EDGES;
}

// P3: partition (src,dst) pairs into bucket-contiguous regions of tmp.
__global__ __launch_bounds__(256) void k_part(const int* __restrict__ src,
                                              const int* __restrict__ dst,
                                              const int* __restrict__ hist,
                                              const int* __restrict__ bucket_base,
                                              int2* __restrict__ tmp) {
    __shared__ int cur[NBUCK];
    int tid = threadIdx.x, blk = blockIdx.x;
    for (int i = tid; i < NBUCK; i += 256)
        cur[i] = bucket_base[i] + hist[blk * NBUCK + i];
    __syncthreads();
    int e0 = blk * CHUNK;
    for (int e = e0 + tid; e < e0 + CHUNK; e += 256) {
        int s = src[e], d = dst[e];
        int slot = atomicAdd(&cur[d >> 7], 1);
        int2 pk; pk.x = s; pk.y = d;
        tmp[slot] = pk;
    }
}

// P4: one block per bucket. Count 128 node degrees in LDS, LDS-scan ->
// deg/row_start/dinv (sequential writes), then place csr_src within the
// bucket's L2-hot ~16KB window.
__global__ __launch_bounds__(256) void k_bucket(const int2* __restrict__ tmp,
                                                const int* __restrict__ bucket_base,
                                                int* __restrict__ deg_cnt,
                                                int* __restrict__ row_start,
                                                float* __restrict__ dinv,
                                                int* __restrict__ csr_src) {
    __shared__ int lcnt[128];
    __shared__ int sc[128];
    __shared__ int lcur[128];
    int tid = threadIdx.x, b = blockIdx.x;
    int lo = bucket_base[b], hi = bucket_base[b + 1];
    if (tid < 128) lcnt[tid] = 0;
    __syncthreads();
    for (int e = lo + tid; e < hi; e += 256)
        atomicAdd(&lcnt[tmp[e].y & 127], 1);
    __syncthreads();
    int c = (tid < 128) ? lcnt[tid] : 0;
    if (tid < 128) sc[tid] = c;
    __syncthreads();
    for (int off = 1; off < 128; off <<= 1) {
        int add = (tid < 128 && tid >= off) ? sc[tid - off] : 0;
        __syncthreads();
        if (tid < 128) sc[tid] += add;
        __syncthreads();
    }
    if (tid < 128) {
        int node = (b << 7) + tid;
        int excl = lo + sc[tid] - c;
        lcur[tid] = excl;
        if (node < N_NODES) {
            deg_cnt[node]   = c;
            row_start[node] = excl;
            dinv[node]      = rsqrtf((float)(c + 1));
        }
    }
    __syncthreads();
    for (int e = lo + tid; e < hi; e += 256) {
        int2 pk = tmp[e];
        int slot = atomicAdd(&lcur[pk.y & 127], 1);
        csr_src[slot] = pk.x;
    }
}

// Pre-swizzle W (128x128 f32, row-major W[k][n]) into MFMA B-fragment order (bf16):
// frag t = (kc*8+nt)*64+lane holds 8 bf16: W[kc*32+(lane>>4)*8+j][nt*16+(lane&15)]
__global__ void k_swz(const float* __restrict__ W, u16* __restrict__ Wz) {
    int t = blockIdx.x * 256 + threadIdx.x;  // 0..2047
    int lane = t & 63, frag = t >> 6;
    int nt = frag & 7, kc = frag >> 3;
    int n  = nt * 16 + (lane & 15);
    int kb = kc * 32 + (lane >> 4) * 8;
    u16 tmp[8];
#pragma unroll
    for (int j = 0; j < 8; ++j) tmp[j] = f2bf(W[(kb + j) * 128 + n]);
#pragma unroll
    for (int j = 0; j < 8; ++j) Wz[t * 8 + j] = tmp[j];
}

// ---- GEMM: Hb[M x 128](bf16) = (act(A) @ W) * dinv[row]
//   ABF16: A is packed bf16 (u32 pairs, 64/row); else f32.
//   FUSE:  act = leaky(A*scale+shift)

template <bool FUSE, bool ABF16>
__global__ __launch_bounds__(256) void k_gemm(const void* __restrict__ Ap,
                                              const u16* __restrict__ Wz,
                                              const float* __restrict__ scale,
                                              const float* __restrict__ shift,
                                              const float* __restrict__ dinv,
                                              u16* __restrict__ Hb, int M) {
    __shared__ u16 wl[16384];  // 32 KB
    __shared__ float sLds[128], hLds[128];
    int tid = threadIdx.x;
    {
        const uint4* s4 = (const uint4*)Wz;
        uint4* d4 = (uint4*)wl;
        for (int i = tid; i < 2048; i += 256) d4[i] = s4[i];
    }
    if (FUSE && tid < 128) { sLds[tid] = scale[tid]; hLds[tid] = shift[tid]; }
    __syncthreads();
    int wave = tid >> 6, lane = tid & 63;
    long m0 = ((long)blockIdx.x * 4 + wave) * 16;
    if (m0 >= M) return;
    int mr = lane & 15, quad = lane >> 4;
    f32x4 acc[8] = {};
#pragma unroll
    for (int kc = 0; kc < 4; ++kc) {
        float av[8];
        if (ABF16) {
            const u32* arow = (const u32*)Ap + (size_t)(m0 + mr) * 64;
            uint4 aw = ((const uint4*)arow)[kc * 4 + quad];
            av[0] = bf_lo(aw.x); av[1] = bf_hi(aw.x);
            av[2] = bf_lo(aw.y); av[3] = bf_hi(aw.y);
            av[4] = bf_lo(aw.z); av[5] = bf_hi(aw.z);
            av[6] = bf_lo(aw.w); av[7] = bf_hi(aw.w);
        } else {
            const float* arow = (const float*)Ap + (size_t)(m0 + mr) * 128 + quad * 8;
            float4 a0 = *(const float4*)(arow + kc * 32);
            float4 a1 = *(const float4*)(arow + kc * 32 + 4);
            av[0] = a0.x; av[1] = a0.y; av[2] = a0.z; av[3] = a0.w;
            av[4] = a1.x; av[5] = a1.y; av[6] = a1.z; av[7] = a1.w;
        }
        if (FUSE) {
            int c = kc * 32 + quad * 8;
#pragma unroll
            for (int j = 0; j < 8; ++j) {
                float v = fmaf(av[j], sLds[c + j], hLds[c + j]);
                av[j] = v > 0.f ? v : v * SLOPE;
            }
        }
        bf16x8 af;
#pragma unroll
        for (int j = 0; j < 8; ++j) af[j] = (short)f2bf(av[j]);
        const u16* wb = wl + (kc * 4096 + lane * 8);  // fragment (kc,nt) at (kc*8+nt)*512
#pragma unroll
        for (int nt = 0; nt < 8; ++nt) {
            bf16x8 bf = *(const bf16x8*)(wb + nt * 512);
            acc[nt] = __builtin_amdgcn_mfma_f32_16x16x32_bf16(af, bf, acc[nt], 0, 0, 0);
        }
    }
    // C/D layout: col = lane&15, row = quad*4 + r ; scale row by dinv, store bf16
    float dr[4];
#pragma unroll
    for (int r = 0; r < 4; ++r) dr[r] = dinv[m0 + quad * 4 + r];
    u16* hb = Hb + (size_t)m0 * 128 + (lane & 15);
#pragma unroll
    for (int nt = 0; nt < 8; ++nt)
#pragma unroll
        for (int r = 0; r < 4; ++r)
            hb[(size_t)(quad * 4 + r) * 128 + nt * 16] = f2bf(acc[nt][r] * dr[r]);
}

// ---------------- aggregation ----------------
// One wave per node; row = 16 uint4; 4 row-groups per wave -> 4 gathers in flight.
// AGGb[d] = bf16( dinv[d] * (sum_{s in N(d)} h'[s] + h'[d]) )   (norm folded into h')

__device__ __forceinline__ void accum8(float* acc, uint4 w, float wt) {
    acc[0] = fmaf(bf_lo(w.x), wt, acc[0]);
    acc[1] = fmaf(bf_hi(w.x), wt, acc[1]);
    acc[2] = fmaf(bf_lo(w.y), wt, acc[2]);
    acc[3] = fmaf(bf_hi(w.y), wt, acc[3]);
    acc[4] = fmaf(bf_lo(w.z), wt, acc[4]);
    acc[5] = fmaf(bf_hi(w.z), wt, acc[5]);
    acc[6] = fmaf(bf_lo(w.w), wt, acc[6]);
    acc[7] = fmaf(bf_hi(w.w), wt, acc[7]);
}
__device__ __forceinline__ void add8(float* acc, uint4 w) {
    acc[0] += bf_lo(w.x); acc[1] += bf_hi(w.x);
    acc[2] += bf_lo(w.y); acc[3] += bf_hi(w.y);
    acc[4] += bf_lo(w.z); acc[5] += bf_hi(w.z);
    acc[6] += bf_lo(w.w); acc[7] += bf_hi(w.w);
}

__global__ __launch_bounds__(256) void k_agg(const uint4* __restrict__ Hb4,
                                             const int* __restrict__ row_start,
                                             const int* __restrict__ cnt,
                                             const float* __restrict__ dinv,
                                             const int* __restrict__ csr_src,
                                             u32* __restrict__ AGGb) {
    int wave = threadIdx.x >> 6, lane = threadIdx.x & 63;
    int node = blockIdx.x * 4 + wave;  // 25000*4 = 100000 exact
    int g = lane >> 4, f = lane & 15;
    int start = row_start[node];
    int num   = cnt[node];
    float di  = dinv[node];
    uint4 selfw = Hb4[(size_t)node * 16 + f];
    float acc[8] = {0.f, 0.f, 0.f, 0.f, 0.f, 0.f, 0.f, 0.f};
    for (int base = 0; base < num; base += 64) {
        int nb = num - base; if (nb > 64) nb = 64;
        int pk = (lane < nb) ? csr_src[start + base + lane] : 0;
        int full = nb & ~15;
        int j = 0;
        for (; j < full; j += 16) {                 // unmasked full blocks
            int s0 = __shfl(pk, j + g),      s1 = __shfl(pk, j + 4 + g);
            int s2 = __shfl(pk, j + 8 + g),  s3 = __shfl(pk, j + 12 + g);
            uint4 a0 = Hb4[(size_t)s0 * 16 + f];
            uint4 a1 = Hb4[(size_t)s1 * 16 + f];
            uint4 a2 = Hb4[(size_t)s2 * 16 + f];
            uint4 a3 = Hb4[(size_t)s3 * 16 + f];
            add8(acc, a0); add8(acc, a1); add8(acc, a2); add8(acc, a3);
        }
        if (j < nb) {                               // one masked tail block
            int j0 = j + g, j1 = j + 4 + g, j2 = j + 8 + g, j3 = j + 12 + g;
            int s0 = __shfl(pk, j0 & 63), s1 = __shfl(pk, j1 & 63);
            int s2 = __shfl(pk, j2 & 63), s3 = __shfl(pk, j3 & 63);
            float w0 = j0 < nb ? 1.f : 0.f, w1 = j1 < nb ? 1.f : 0.f;
            float w2 = j2 < nb ? 1.f : 0.f, w3 = j3 < nb ? 1.f : 0.f;
            uint4 a0 = Hb4[(size_t)s0 * 16 + f];
            uint4 a1 = Hb4[(size_t)s1 * 16 + f];
            uint4 a2 = Hb4[(size_t)s2 * 16 + f];
            uint4 a3 = Hb4[(size_t)s3 * 16 + f];
            accum8(acc, a0, w0); accum8(acc, a1, w1);
            accum8(acc, a2, w2); accum8(acc, a3, w3);
        }
    }
#pragma unroll
    for (int i = 0; i < 8; ++i) {
        acc[i] += __shfl_xor(acc[i], 16);
        acc[i] += __shfl_xor(acc[i], 32);
    }
    add8(acc, selfw);                 // + h'[d]
#pragma unroll
    for (int i = 0; i < 8; ++i) acc[i] *= di;
    if (g == 0) {                     // all groups hold the full sum; one writes
        u32 p0 = (u32)f2bf(acc[0]) | ((u32)f2bf(acc[1]) << 16);
        u32 p1 = (u32)f2bf(acc[2]) | ((u32)f2bf(acc[3]) << 16);
        u32 p2 = (u32)f2bf(acc[4]) | ((u32)f2bf(acc[5]) << 16);
        u32 p3 = (u32)f2bf(acc[6]) | ((u32)f2bf(acc[7]) << 16);
        uint4 o; o.x = p0; o.y = p1; o.z = p2; o.w = p3;
        ((uint4*)(AGGb + (size_t)node * 64))[f] = o;
    }
}

// ---------------- batch norm (bf16 AGG input) ----------------

__global__ void k_bnstats(const u32* __restrict__ AGGb, float* __restrict__ sums,
                          float* __restrict__ sumsq) {
    __shared__ float red[256];
    int col  = threadIdx.x & 127;
    int half = threadIdx.x >> 7;
    int odd  = col & 1, c2 = col >> 1;
    long r0 = (long)blockIdx.x * 400 + half;  // 250 blocks * 400 rows = 100000
    float s = 0.f, s2 = 0.f;
    for (int k = 0; k < 400; k += 2) {
        u32 w = AGGb[(r0 + k) * 64 + c2];
        float v = odd ? bf_hi(w) : bf_lo(w);
        s += v;
        s2 = fmaf(v, v, s2);
    }
    red[threadIdx.x] = s; __syncthreads();
    if (threadIdx.x < 128) atomicAdd(&sums[col], red[threadIdx.x] + red[threadIdx.x + 128]);
    __syncthreads();
    red[threadIdx.x] = s2; __syncthreads();
    if (threadIdx.x < 128) atomicAdd(&sumsq[col], red[threadIdx.x] + red[threadIdx.x + 128]);
}

__global__ void k_bnfin(const float* __restrict__ sums, const float* __restrict__ sumsq,
                        const float* __restrict__ g, const float* __restrict__ be,
                        float* __restrict__ scale, float* __restrict__ shift) {
    int c = threadIdx.x;  // 128 threads
    float mean = sums[c] * (1.f / N_NODES);
    float var  = sumsq[c] * (1.f / N_NODES) - mean * mean;
    float rstd = rsqrtf(var + EPSBN);
    float gg = g[c] * rstd;
    scale[c] = gg;
    shift[c] = be[c] - mean * gg;
}

// out = leaky(agg*scale + shift + x), f32 out; AGG is bf16-packed
__global__ void k_ew2(const u32* __restrict__ AGGb, const float* __restrict__ scale,
                      const float* __restrict__ shift, const float* __restrict__ x,
                      float* __restrict__ out) {
    long i = (long)blockIdx.x * 256 + threadIdx.x;  // one u32 / float2 per thread
    int c2 = (int)(i & 63);
    u32 w = AGGb[i];
    float2 sc = ((const float2*)scale)[c2];
    float2 sh = ((const float2*)shift)[c2];
    float2 xv = ((const float2*)x)[i];
    float2 o;
    o.x = fmaf(bf_lo(w), sc.x, sh.x) + xv.x; o.x = o.x > 0.f ? o.x : o.x * SLOPE;
    o.y = fmaf(bf_hi(w), sc.y, sh.y) + xv.y; o.y = o.y > 0.f ? o.y : o.y * SLOPE;
    ((float2*)out)[i] = o;
}

// ---------------- launch ----------------

extern "C" void kernel_launch(void* const* d_in, const int* in_sizes, int n_in,
                              void* d_out, int out_size, void* d_ws, size_t ws_size,
                              hipStream_t stream) {
    const float* x   = (const float*)d_in[0];
    const int*   ei  = (const int*)d_in[1];
    const float* W1  = (const float*)d_in[2];
    const float* g1  = (const float*)d_in[4];
    const float* be1 = (const float*)d_in[5];
    const float* W2  = (const float*)d_in[6];
    const float* g2  = (const float*)d_in[8];
    const float* be2 = (const float*)d_in[9];
    const int* src = ei;
    const int* dst = ei + N_EDGES;

    float* out = (float*)d_out;
    u16*   Hb  = (u16*)d_out;  // 25.6 MB bf16 H lives in d_out until ew2 overwrites it

    char* p = (char*)d_ws;
    u32*   aggb    = (u32*)p;   p += (size_t)N_NODES * 64 * 4;   // 25.6 MB bf16 AGG
    int2*  tmp     = (int2*)p;  p += (size_t)N_EDGES * 8;        // 12.8 MB bucketed pairs
    int*   csr_src = (int*)p;   p += (size_t)N_EDGES * 4;        // 6.4 MB
    int*   hist    = (int*)p;   p += (size_t)PBLK * NBUCK * 4;   // 0.8 MB
    int*   tot     = (int*)p;   p += 1024 * 4;
    int*   bbase   = (int*)p;   p += 1024 * 4;
    int*   deg_cnt = (int*)p;   p += (size_t)N_NODES * 4;
    int*   row_st  = (int*)p;   p += (size_t)N_NODES * 4;
    float* dinv    = (float*)p; p += (size_t)N_NODES * 4;
    float* stats   = (float*)p; p += 1024 * 4;
    u16*   wz1     = (u16*)p;   p += 16384 * 2;
    u16*   wz2     = (u16*)p;   p += 16384 * 2;

    float* sums1 = stats,       *sq1 = stats + 128, *scale1 = stats + 256, *shift1 = stats + 384;
    float* sums2 = stats + 512, *sq2 = stats + 640, *scale2 = stats + 768, *shift2 = stats + 896;

    // graph setup: histogram -> bucket bases -> partition -> per-bucket
    // degree-count/scan/place (all counting via LDS; no global atomics)
    k_init<<<4, 256, 0, stream>>>(stats);
    k_hist<<<PBLK, 256, 0, stream>>>(dst, hist);
    k_colscan<<<NBUCK, 256, 0, stream>>>(hist, tot);
    k_bscan<<<1, 1024, 0, stream>>>(tot, bbase);
    k_part<<<PBLK, 256, 0, stream>>>(src, dst, hist, bbase, tmp);
    k_bucket<<<NBUCK, 256, 0, stream>>>(tmp, bbase, deg_cnt, row_st, dinv, csr_src);
    k_swz<<<8, 256, 0, stream>>>(W1, wz1);
    k_swz<<<8, 256, 0, stream>>>(W2, wz2);

    // layer 1:  Hb1 = (x@W1)*dinv -> d_out (bf16),  AGG1(bf16) -> aggb
    k_gemm<false, false><<<1563, 256, 0, stream>>>(x, wz1, nullptr, nullptr, dinv, Hb, N_NODES);
    k_agg<<<25000, 256, 0, stream>>>((const uint4*)Hb, row_st, deg_cnt, dinv, csr_src, aggb);
    k_bnstats<<<250, 256, 0, stream>>>(aggb, sums1, sq1);
    k_bnfin<<<1, 128, 0, stream>>>(sums1, sq1, g1, be1, scale1, shift1);

    // layer 2:  Hb2 = (leaky(BN1(AGG1))@W2)*dinv -> d_out;  AGG2(bf16) -> aggb
    k_gemm<true, true><<<1563, 256, 0, stream>>>(aggb, wz2, scale1, shift1, dinv, Hb, N_NODES);
    k_agg<<<25000, 256, 0, stream>>>((const uint4*)Hb, row_st, deg_cnt, dinv, csr_src, aggb);
    k_bnstats<<<250, 256, 0, stream>>>(aggb, sums2, sq2);
    k_bnfin<<<1, 128, 0, stream>>>(sums2, sq2, g2, be2, scale2, shift2);
    k_ew2<<<25000, 256, 0, stream>>>(aggb, scale2, shift2, x, out);
}